// Round 5
// baseline (1016.998 us; speedup 1.0000x reference)
//
#include <hip/hip_runtime.h>
#include <math.h>

// Problem constants
#define LAYERS 6
#define DMODEL 512
#define NHEAD 8
#define DHEAD 64
#define FFDIM 2048
#define BATCH 8
#define SEQ 1024
#define ROWS (BATCH * SEQ)   // 8192
#define EPS 1e-5f

typedef __attribute__((ext_vector_type(8))) short bf16x8;
typedef __attribute__((ext_vector_type(4))) float f32x4;
typedef __attribute__((ext_vector_type(16))) float f32x16;

__device__ inline short f2bf(float f) {
    union { float f; unsigned u; } v; v.f = f;
    unsigned r = (v.u + 0x7FFFu + ((v.u >> 16) & 1u)) >> 16;
    return (short)r;
}

// async global(bf16,16B) -> LDS staging; data lands at wave-uniform base + lane*16
#define GLOAD_LDS16(g, l)                                                      \
    __builtin_amdgcn_global_load_lds(                                          \
        (__attribute__((address_space(1))) void*)(g),                          \
        (__attribute__((address_space(3))) void*)(l), 16, 0, 0)

// XCD-chunked bijective block swizzle (nwg % 8 == 0 for all call sites):
// hw block h runs on XCD h%8; give XCD x the contiguous tile chunk
// [x*chunk, (x+1)*chunk) so A-panels are reused within one XCD's L2.
#define XCD_SWIZZLE(TM)                                                        \
    const int gx_ = gridDim.x;                                                 \
    const int bid_ = blockIdx.x + gx_ * blockIdx.y;                            \
    const int chunk_ = (gx_ * gridDim.y) >> 3;                                 \
    const int nb_ = (bid_ & 7) * chunk_ + (bid_ >> 3);                         \
    const int m0 = (nb_ / gx_) * (TM);                                         \
    const int n0 = (nb_ % gx_) * 128;

// ---------------------------------------------------------------------------
// Weight transpose + fp32->bf16: src [L][K][N] f32 -> dst [L][N][K] bf16
// ---------------------------------------------------------------------------
__global__ void wtrans_kernel(const float* __restrict__ src, short* __restrict__ dst,
                              int K, int N) {
    __shared__ float t[32][33];
    const size_t mofs = (size_t)blockIdx.z * K * N;
    src += mofs; dst += mofs;
    int n0 = blockIdx.x * 32, k0 = blockIdx.y * 32;
    int tx = threadIdx.x, ty = threadIdx.y;
#pragma unroll
    for (int i = 0; i < 4; ++i)
        t[ty + 8 * i][tx] = src[(size_t)(k0 + ty + 8 * i) * N + n0 + tx];
    __syncthreads();
#pragma unroll
    for (int i = 0; i < 4; ++i)
        dst[(size_t)(n0 + ty + 8 * i) * K + k0 + tx] = f2bf(t[tx][ty + 8 * i]);
}

// ---------------------------------------------------------------------------
// Positional scan
// ---------------------------------------------------------------------------
__global__ void pos_scan_kernel(const int* __restrict__ mask, int* __restrict__ pos) {
    __shared__ int sm[SEQ];
    int b = blockIdx.x;
    int t = threadIdx.x;
    int v = (mask[b * SEQ + t] != 0) ? 1 : 0;
    sm[t] = v;
    __syncthreads();
    for (int off = 1; off < SEQ; off <<= 1) {
        int add = (t >= off) ? sm[t - off] : 0;
        __syncthreads();
        sm[t] += add;
        __syncthreads();
    }
    pos[b * SEQ + t] = sm[t] * v;
}

// ---------------------------------------------------------------------------
// x = x_in + sin_pos_table[pos]; writes fp32 master + bf16 copy
// ---------------------------------------------------------------------------
__global__ void add_pos_kernel(const float* __restrict__ xin, const int* __restrict__ pos,
                               float* __restrict__ xout, short* __restrict__ xb) {
    int bs = blockIdx.x;
    int t = threadIdx.x;
    int p = pos[bs];
    int d0 = t * 4;
    const float C = -logf(10000.0f) * (1.0f / 255.0f);  // half-1 = 255
    float4 xv = *(const float4*)(xin + (size_t)bs * DMODEL + d0);
    float e[4];
#pragma unroll
    for (int j = 0; j < 4; ++j) {
        int d = d0 + j;
        if (p == 0) {
            e[j] = 0.0f;
        } else {
            int dd = (d < 256) ? d : d - 256;
            float freq = expf((float)dd * C);
            float ang = (float)p * freq;
            e[j] = (d < 256) ? sinf(ang) : cosf(ang);
        }
    }
    float4 ov;
    ov.x = xv.x + e[0]; ov.y = xv.y + e[1]; ov.z = xv.z + e[2]; ov.w = xv.w + e[3];
    *(float4*)(xout + (size_t)bs * DMODEL + d0) = ov;
    short4 sb;
    sb.x = f2bf(ov.x); sb.y = f2bf(ov.y); sb.z = f2bf(ov.z); sb.w = f2bf(ov.w);
    *(short4*)(xb + (size_t)bs * DMODEL + d0) = sb;
}

// ===========================================================================
// LDS k-granule swizzle (both GEMM kernels):
//   store: staging lane (r=lane>>2, pos=lane&3) fetches global granule
//          g' = (pos - (r>>1)) & 3  -> granule q of row m lands at LDS
//          position (q + ((m&15)>>1)) & 3.
//   read:  fragment (m, quad) at granule position (quad + (lr>>1)) & 3.
//   Result: conflict-free ds_read_b128.
//
// K-loop (both GEMMs): 3-buffer ring + raw s_barrier + COUNTED vmcnt (T4).
//   iter i: wait vmcnt(L) (L = loads/tile) so only tile i's loads must have
//   retired -- tile i+1's prefetch stays IN FLIGHT across the barrier; then
//   stage tile i+2 post-barrier. lgkmcnt(0) before the barrier drains this
//   wave's ds_reads of the buffer that stage(i+2) will overwrite.
//   Last iteration waits vmcnt(0). sched_barrier(0) fences hoisting.
// ===========================================================================

// ---------------------------------------------------------------------------
// bf16 MFMA GEMM, 128x128 tile, BK=32, 256 thr, 3-ring counted-vmcnt pipeline.
// C[M,N] = A[M,K] @ BT[N,K]^T (+bias)(+relu).
// ---------------------------------------------------------------------------
template <bool OUTBF16, bool BIAS, bool RELU>
__global__ __launch_bounds__(256) void gemm_bf16_kernel(const short* __restrict__ A,
                                                        const short* __restrict__ BT,
                                                        const float* __restrict__ bias,
                                                        void* __restrict__ Cv,
                                                        int M, int N, int K) {
    __shared__ __attribute__((aligned(16))) short Asm[3][128 * 32];
    __shared__ __attribute__((aligned(16))) short Bsm[3][128 * 32];
    const int tid = threadIdx.x;
    const int w = tid >> 6;
    const int lane = tid & 63;
    const int quad = lane >> 4;
    const int lr = lane & 15;
    XCD_SWIZZLE(128)
    const int wm = (w >> 1) * 64;
    const int wn = (w & 1) * 64;

    // staging: 8 segments of 16 rows; wave w owns segs {2w, 2w+1}
    const int segr = lane >> 2;
    const int segk = (((lane & 3) - (lane >> 3)) & 3) * 8;  // swizzled source granule
    const int sA0 = w * 2, sA1 = w * 2 + 1;
    const short* gA0 = A + (size_t)(m0 + sA0 * 16 + segr) * K + segk;
    const short* gA1 = A + (size_t)(m0 + sA1 * 16 + segr) * K + segk;
    const short* gB0 = BT + (size_t)(n0 + sA0 * 16 + segr) * K + segk;
    const short* gB1 = BT + (size_t)(n0 + sA1 * 16 + segr) * K + segk;
    const int lofs0 = sA0 * 512 + lane * 8;
    const int lofs1 = sA1 * 512 + lane * 8;
    const int gp = ((quad + (lr >> 1)) & 3) * 8;            // swizzled read position

    f32x4 acc[4][4];
#pragma unroll
    for (int i = 0; i < 4; ++i)
#pragma unroll
        for (int j = 0; j < 4; ++j) { acc[i][j][0] = 0.f; acc[i][j][1] = 0.f; acc[i][j][2] = 0.f; acc[i][j][3] = 0.f; }

    // prologue: stage k-tiles 0 and 1 (8 loads outstanding)
    GLOAD_LDS16(gA0, &Asm[0][lofs0]);
    GLOAD_LDS16(gA1, &Asm[0][lofs1]);
    GLOAD_LDS16(gB0, &Bsm[0][lofs0]);
    GLOAD_LDS16(gB1, &Bsm[0][lofs1]);
    GLOAD_LDS16(gA0 + 32, &Asm[1][lofs0]);
    GLOAD_LDS16(gA1 + 32, &Asm[1][lofs1]);
    GLOAD_LDS16(gB0 + 32, &Bsm[1][lofs0]);
    GLOAD_LDS16(gB1 + 32, &Bsm[1][lofs1]);

    const int nk = K >> 5;
    int cur = 0, sb = 2;
    for (int i = 0; i < nk; ++i) {
        // counted wait: tile i retired, tile i+1 stays in flight
        if (i + 1 < nk)
            asm volatile("s_waitcnt vmcnt(4) lgkmcnt(0)" ::: "memory");
        else
            asm volatile("s_waitcnt vmcnt(0) lgkmcnt(0)" ::: "memory");
        __builtin_amdgcn_sched_barrier(0);
        __builtin_amdgcn_s_barrier();
        __builtin_amdgcn_sched_barrier(0);
        if (i + 2 < nk) {
            const int k2 = (i + 2) * 32;
            GLOAD_LDS16(gA0 + k2, &Asm[sb][lofs0]);
            GLOAD_LDS16(gA1 + k2, &Asm[sb][lofs1]);
            GLOAD_LDS16(gB0 + k2, &Bsm[sb][lofs0]);
            GLOAD_LDS16(gB1 + k2, &Bsm[sb][lofs1]);
        }
        bf16x8 af[4], bfr[4];
#pragma unroll
        for (int mt = 0; mt < 4; ++mt)
            af[mt] = *(const bf16x8*)&Asm[cur][(wm + mt * 16 + lr) * 32 + gp];
#pragma unroll
        for (int nt = 0; nt < 4; ++nt)
            bfr[nt] = *(const bf16x8*)&Bsm[cur][(wn + nt * 16 + lr) * 32 + gp];
        __builtin_amdgcn_s_setprio(1);
#pragma unroll
        for (int mt = 0; mt < 4; ++mt)
#pragma unroll
            for (int nt = 0; nt < 4; ++nt)
                acc[mt][nt] = __builtin_amdgcn_mfma_f32_16x16x32_bf16(af[mt], bfr[nt], acc[mt][nt], 0, 0, 0);
        __builtin_amdgcn_s_setprio(0);
        cur = (cur == 2) ? 0 : cur + 1;
        sb = (sb == 2) ? 0 : sb + 1;
    }

    float bv[4];
    if (BIAS) {
#pragma unroll
        for (int nt = 0; nt < 4; ++nt) bv[nt] = bias[n0 + wn + nt * 16 + lr];
    }
#pragma unroll
    for (int mt = 0; mt < 4; ++mt)
#pragma unroll
        for (int nt = 0; nt < 4; ++nt)
#pragma unroll
            for (int r = 0; r < 4; ++r) {
                float v = acc[mt][nt][r];
                if (BIAS) v += bv[nt];
                if (RELU) v = fmaxf(v, 0.f);
                int row = m0 + wm + mt * 16 + quad * 4 + r;
                int col = n0 + wn + nt * 16 + lr;
                if (OUTBF16)
                    ((short*)Cv)[(size_t)row * N + col] = f2bf(v);
                else
                    ((float*)Cv)[(size_t)row * N + col] = v;
            }
}

// ---------------------------------------------------------------------------
// bf16 MFMA GEMM, 64x128 tile, BK=64, 3-ring counted-vmcnt pipeline (6 loads
// per k-tile -> steady vmcnt(6)). 256 thr = 4 waves. LDS 72 KB -> 2 blocks/CU.
// ---------------------------------------------------------------------------
template <bool OUTBF16, bool BIAS, bool RELU>
__global__ __launch_bounds__(256) void gemm_bf16_m64_kernel(const short* __restrict__ A,
                                                            const short* __restrict__ BT,
                                                            const float* __restrict__ bias,
                                                            void* __restrict__ Cv,
                                                            int M, int N, int K) {
    __shared__ __attribute__((aligned(16))) short Asm[3][2][64 * 32];
    __shared__ __attribute__((aligned(16))) short Bsm[3][2][128 * 32];
    const int tid = threadIdx.x;
    const int w = tid >> 6;
    const int lane = tid & 63;
    const int quad = lane >> 4;
    const int lr = lane & 15;
    XCD_SWIZZLE(64)
    const int wm = (w >> 1) * 32;
    const int wn = (w & 1) * 64;

    // staging: A = 4 segs (wave w -> seg w), B = 8 segs (wave w -> 2w, 2w+1)
    const int segr = lane >> 2;
    const int segk = (((lane & 3) - (lane >> 3)) & 3) * 8;  // swizzled source granule
    const short* gA  = A + (size_t)(m0 + w * 16 + segr) * K + segk;
    const short* gB0 = BT + (size_t)(n0 + (2 * w) * 16 + segr) * K + segk;
    const short* gB1 = BT + (size_t)(n0 + (2 * w + 1) * 16 + segr) * K + segk;
    const int lA  = w * 512 + lane * 8;
    const int lB0 = (2 * w) * 512 + lane * 8;
    const int lB1 = (2 * w + 1) * 512 + lane * 8;
    const int gp = ((quad + (lr >> 1)) & 3) * 8;            // swizzled read position

    f32x4 acc[2][4];
#pragma unroll
    for (int i = 0; i < 2; ++i)
#pragma unroll
        for (int j = 0; j < 4; ++j) { acc[i][j][0] = 0.f; acc[i][j][1] = 0.f; acc[i][j][2] = 0.f; acc[i][j][3] = 0.f; }

    // prologue: stage k-tiles 0 and 1 (12 loads outstanding)
#pragma unroll
    for (int kh = 0; kh < 2; ++kh) {
        GLOAD_LDS16(gA + kh * 32, &Asm[0][kh][lA]);
        GLOAD_LDS16(gB0 + kh * 32, &Bsm[0][kh][lB0]);
        GLOAD_LDS16(gB1 + kh * 32, &Bsm[0][kh][lB1]);
    }
#pragma unroll
    for (int kh = 0; kh < 2; ++kh) {
        GLOAD_LDS16(gA + 64 + kh * 32, &Asm[1][kh][lA]);
        GLOAD_LDS16(gB0 + 64 + kh * 32, &Bsm[1][kh][lB0]);
        GLOAD_LDS16(gB1 + 64 + kh * 32, &Bsm[1][kh][lB1]);
    }

    const int nk = K >> 6;
    int cur = 0, sb = 2;
    for (int i = 0; i < nk; ++i) {
        if (i + 1 < nk)
            asm volatile("s_waitcnt vmcnt(6) lgkmcnt(0)" ::: "memory");
        else
            asm volatile("s_waitcnt vmcnt(0) lgkmcnt(0)" ::: "memory");
        __builtin_amdgcn_sched_barrier(0);
        __builtin_amdgcn_s_barrier();
        __builtin_amdgcn_sched_barrier(0);
        if (i + 2 < nk) {
            const int k2 = (i + 2) * 64;
#pragma unroll
            for (int kh = 0; kh < 2; ++kh) {
                GLOAD_LDS16(gA + k2 + kh * 32, &Asm[sb][kh][lA]);
                GLOAD_LDS16(gB0 + k2 + kh * 32, &Bsm[sb][kh][lB0]);
                GLOAD_LDS16(gB1 + k2 + kh * 32, &Bsm[sb][kh][lB1]);
            }
        }
#pragma unroll
        for (int kh = 0; kh < 2; ++kh) {
            bf16x8 af[2], bfr[4];
#pragma unroll
            for (int mt = 0; mt < 2; ++mt)
                af[mt] = *(const bf16x8*)&Asm[cur][kh][(wm + mt * 16 + lr) * 32 + gp];
#pragma unroll
            for (int nt = 0; nt < 4; ++nt)
                bfr[nt] = *(const bf16x8*)&Bsm[cur][kh][(wn + nt * 16 + lr) * 32 + gp];
            __builtin_amdgcn_s_setprio(1);
#pragma unroll
            for (int mt = 0; mt < 2; ++mt)
#pragma unroll
                for (int nt = 0; nt < 4; ++nt)
                    acc[mt][nt] = __builtin_amdgcn_mfma_f32_16x16x32_bf16(af[mt], bfr[nt], acc[mt][nt], 0, 0, 0);
            __builtin_amdgcn_s_setprio(0);
        }
        cur = (cur == 2) ? 0 : cur + 1;
        sb = (sb == 2) ? 0 : sb + 1;
    }

    float bv[4];
    if (BIAS) {
#pragma unroll
        for (int nt = 0; nt < 4; ++nt) bv[nt] = bias[n0 + wn + nt * 16 + lr];
    }
#pragma unroll
    for (int mt = 0; mt < 2; ++mt)
#pragma unroll
        for (int nt = 0; nt < 4; ++nt)
#pragma unroll
            for (int r = 0; r < 4; ++r) {
                float v = acc[mt][nt][r];
                if (BIAS) v += bv[nt];
                if (RELU) v = fmaxf(v, 0.f);
                int row = m0 + wm + mt * 16 + quad * 4 + r;
                int col = n0 + wn + nt * 16 + lr;
                if (OUTBF16)
                    ((short*)Cv)[(size_t)row * N + col] = f2bf(v);
                else
                    ((float*)Cv)[(size_t)row * N + col] = v;
            }
}

// ---------------------------------------------------------------------------
// bf16-MFMA flash attention v4b: 32x32x16 MFMA shape. QTILE=256, 512 thr =
// 8 waves x 32 q-rows. Swapped QK^T (S^T = mfma(K, Q)) leaves P^T[key][q]
// in registers; the PV A-fragment is built fully IN-REGISTER via
// cvt_pk_bf16 + cross-half shfl_xor(32) + select (no P LDS round-trip).
// Mask+shift folded into the exp ARGUMENT (additive -8 / -1e30 bias table).
// s_setprio(1) around MFMA clusters (T5). No-rescale softmax (fixed shift 8,
// exact after normalization), double-buffered K/V staging, ONE barrier/tile.
//
// Layouts (mfma_f32_32x32x16_bf16):
//   A:  row = lane&31, k = (lane>>5)*8 + j   (4 VGPR = 8 bf16)
//   B:  col = lane&31, k = (lane>>5)*8 + j
//   C:  col = lane&31, row = (reg&3) + 8*(reg>>2) + 4*(lane>>5)
// ---------------------------------------------------------------------------
#define QTILE 256
__global__ __launch_bounds__(512, 2) void attn_mfma_kernel(const short* __restrict__ qkv,
                                                           const int* __restrict__ mask,
                                                           short* __restrict__ o) {
    __shared__ __attribute__((aligned(16))) short Ks[2][64][72];    // [key][d]
    __shared__ __attribute__((aligned(16))) short Vt[2][64][72];    // [d][key]
    __shared__ __attribute__((aligned(16))) float Msf[2][64];

    const int qt = blockIdx.x;          // 0..3
    const int bh = blockIdx.y;          // 0..63
    const int b = bh >> 3, h = bh & 7;
    const int tid = threadIdx.x;
    const int w = tid >> 6;             // wave 0..7
    const int lane = tid & 63;
    const int c31 = lane & 31;
    const int hi = lane >> 5;
    const size_t seqrow = (size_t)b * SEQ;

    // Q as B-operand: lane holds Q^T[k=d=16ks+8hi+j][q=c31]
    bf16x8 qf[4];
#pragma unroll
    for (int ks = 0; ks < 4; ++ks)
        qf[ks] = *(const bf16x8*)(qkv +
            (seqrow + qt * QTILE + w * 32 + c31) * (3 * DMODEL)
            + h * DHEAD + ks * 16 + hi * 8);

    const bool isK = (tid < 256);
    const int st = isK ? tid : tid - 256;
    const int kkey = st >> 2;
    const int kg = (st & 3) * 8;
    const int vkp = st & 31;
    const int vdg = st >> 5;
    const short* gK = qkv + (seqrow + kkey) * (3 * DMODEL) + DMODEL + h * DHEAD + kg;
    const short* gV = qkv + (seqrow + 2 * vkp) * (3 * DMODEL) + 2 * DMODEL + h * DHEAD + vdg * 8;

    bf16x8 r0, r1;
    int mreg = 0;

    {
        if (isK) {
            r0 = *(const bf16x8*)(gK);
            r1 = *(const bf16x8*)(gK + 32);
        } else {
            r0 = *(const bf16x8*)(gV);
            r1 = *(const bf16x8*)(gV + 3 * DMODEL);
        }
        if (tid < 64) mreg = mask[seqrow + tid];
        if (isK) {
            *(bf16x8*)&Ks[0][kkey][kg] = r0;
            *(bf16x8*)&Ks[0][kkey][kg + 32] = r1;
        } else {
#pragma unroll
            for (int i = 0; i < 8; ++i) {
                short2 p; p.x = r0[i]; p.y = r1[i];
                *(short2*)&Vt[0][vdg * 8 + i][vkp * 2] = p;
            }
        }
        if (tid < 64) Msf[0][tid] = mreg ? -8.0f : -1e30f;   // additive exp bias
    }
    __syncthreads();

    f32x16 O0, O1;
    float rs = 0.f;
#pragma unroll
    for (int i = 0; i < 16; ++i) { O0[i] = 0.f; O1[i] = 0.f; }

    for (int kt = 0; kt < 16; ++kt) {
        const int cur = kt & 1;
        {
            const size_t ofs = (size_t)((kt + 1) & 15) * 64 * (3 * DMODEL);
            if (isK) {
                r0 = *(const bf16x8*)(gK + ofs);
                r1 = *(const bf16x8*)(gK + ofs + 32);
            } else {
                r0 = *(const bf16x8*)(gV + ofs);
                r1 = *(const bf16x8*)(gV + ofs + 3 * DMODEL);
            }
            if (tid < 64) mreg = mask[seqrow + ((kt + 1) & 15) * 64 + tid];
        }

        // QK^T: S^T[key][q], two 32-key tiles
        f32x16 S0, S1;
#pragma unroll
        for (int i = 0; i < 16; ++i) { S0[i] = 0.f; S1[i] = 0.f; }
        __builtin_amdgcn_s_setprio(1);
#pragma unroll
        for (int ks = 0; ks < 4; ++ks) {
            bf16x8 k0 = *(const bf16x8*)&Ks[cur][c31][ks * 16 + hi * 8];
            bf16x8 k1 = *(const bf16x8*)&Ks[cur][32 + c31][ks * 16 + hi * 8];
            S0 = __builtin_amdgcn_mfma_f32_32x32x16_bf16(k0, qf[ks], S0, 0, 0, 0);
            S1 = __builtin_amdgcn_mfma_f32_32x32x16_bf16(k1, qf[ks], S1, 0, 0, 0);
        }
        __builtin_amdgcn_s_setprio(0);

        // softmax (no rescale; additive bias = -8 or -1e30) + pack to bf16.
        // S reg r holds key = (r&3) + 8*(r>>2) + 4*hi (+32 for S1).
        unsigned pkd[2][8];
#pragma unroll
        for (int g = 0; g < 4; ++g) {
            f32x4 m0 = *(const f32x4*)&Msf[cur][g * 8 + hi * 4];
            f32x4 m1 = *(const f32x4*)&Msf[cur][32 + g * 8 + hi * 4];
            float p0[4], p1[4];
#pragma unroll
            for (int j = 0; j < 4; ++j) {
                p0[j] = __expf(S0[g * 4 + j] + m0[j]);
                p1[j] = __expf(S1[g * 4 + j] + m1[j]);
                rs += p0[j] + p1[j];
            }
            asm("v_cvt_pk_bf16_f32 %0, %1, %2" : "=v"(pkd[0][g * 2])     : "v"(p0[0]), "v"(p0[1]));
            asm("v_cvt_pk_bf16_f32 %0, %1, %2" : "=v"(pkd[0][g * 2 + 1]) : "v"(p0[2]), "v"(p0[3]));
            asm("v_cvt_pk_bf16_f32 %0, %1, %2" : "=v"(pkd[1][g * 2])     : "v"(p1[0]), "v"(p1[1]));
            asm("v_cvt_pk_bf16_f32 %0, %1, %2" : "=v"(pkd[1][g * 2 + 1]) : "v"(p1[2]), "v"(p1[3]));
        }

        // PV: build A-frag per ks in-register.
#pragma unroll
        for (int ks = 0; ks < 4; ++ks) {
            const int k2 = ks >> 1;
            const int i0 = (ks & 1) * 4;
            unsigned c0a = pkd[k2][i0 + 0], c0b = pkd[k2][i0 + 1];
            unsigned c1a = pkd[k2][i0 + 2], c1b = pkd[k2][i0 + 3];
            unsigned x1a = (unsigned)__shfl_xor((int)c1a, 32);
            unsigned x1b = (unsigned)__shfl_xor((int)c1b, 32);
            unsigned x0a = (unsigned)__shfl_xor((int)c0a, 32);
            unsigned x0b = (unsigned)__shfl_xor((int)c0b, 32);
            union { unsigned u[4]; bf16x8 v; } pb;
            pb.u[0] = hi ? x1a : c0a;   // d0: lo->own C0 ; hi->partner C1
            pb.u[1] = hi ? x1b : c0b;   // d1
            pb.u[2] = hi ? c1a : x0a;   // d2: lo->partner C0 ; hi->own C1
            pb.u[3] = hi ? c1b : x0b;   // d3
            bf16x8 v0 = *(const bf16x8*)&Vt[cur][c31][ks * 16 + hi * 8];
            bf16x8 v1 = *(const bf16x8*)&Vt[cur][32 + c31][ks * 16 + hi * 8];
            __builtin_amdgcn_s_setprio(1);
            O0 = __builtin_amdgcn_mfma_f32_32x32x16_bf16(pb.v, v0, O0, 0, 0, 0);
            O1 = __builtin_amdgcn_mfma_f32_32x32x16_bf16(pb.v, v1, O1, 0, 0, 0);
            __builtin_amdgcn_s_setprio(0);
        }

        {
            const int nb = cur ^ 1;
            if (isK) {
                *(bf16x8*)&Ks[nb][kkey][kg] = r0;
                *(bf16x8*)&Ks[nb][kkey][kg + 32] = r1;
            } else {
#pragma unroll
                for (int i = 0; i < 8; ++i) {
                    short2 p; p.x = r0[i]; p.y = r1[i];
                    *(short2*)&Vt[nb][vdg * 8 + i][vkp * 2] = p;
                }
            }
            if (tid < 64) Msf[nb][tid] = mreg ? -8.0f : -1e30f;
        }
        __syncthreads();
    }

    // rs: lane holds partial denominator for q=c31 over its own-half keys.
    rs += __shfl_xor(rs, 32);   // full denominator for q=c31, all lanes

#pragma unroll
    for (int r = 0; r < 16; ++r) {
        const int qr = (r & 3) + 8 * (r >> 2) + 4 * hi;   // O row = q
        const float inv = 1.0f / __shfl(rs, qr);
        const int row = qt * QTILE + w * 32 + qr;
        o[(seqrow + row) * DMODEL + h * DHEAD + c31]      = f2bf(O0[r] * inv);
        o[(seqrow + row) * DMODEL + h * DHEAD + 32 + c31] = f2bf(O1[r] * inv);
    }
}

// ---------------------------------------------------------------------------
// x = LayerNorm(tmp + x) * g + b; writes fp32 master (in-place) + bf16 copy
// ---------------------------------------------------------------------------
__global__ __launch_bounds__(64) void ln_kernel(const float* __restrict__ tmp,
                                                float* __restrict__ x,
                                                short* __restrict__ xb,
                                                const float* __restrict__ g,
                                                const float* __restrict__ bta) {
    const int row = blockIdx.x;
    const int t = threadIdx.x;
    const size_t base = (size_t)row * DMODEL + t * 8;
    float4 x0 = *(const float4*)(x + base);
    float4 x1 = *(const float4*)(x + base + 4);
    float4 t0 = *(const float4*)(tmp + base);
    float4 t1 = *(const float4*)(tmp + base + 4);
    float v[8];
    v[0] = x0.x + t0.x; v[1] = x0.y + t0.y; v[2] = x0.z + t0.z; v[3] = x0.w + t0.w;
    v[4] = x1.x + t1.x; v[5] = x1.y + t1.y; v[6] = x1.z + t1.z; v[7] = x1.w + t1.w;
    float s = 0.f, sq = 0.f;
#pragma unroll
    for (int i = 0; i < 8; ++i) { s += v[i]; sq += v[i] * v[i]; }
#pragma unroll
    for (int off = 1; off < 64; off <<= 1) {
        s += __shfl_xor(s, off);
        sq += __shfl_xor(sq, off);
    }
    float mu = s * (1.0f / DMODEL);
    float var = sq * (1.0f / DMODEL) - mu * mu;
    float r = rsqrtf(var + EPS);
    float4 g0 = *(const float4*)(g + t * 8);
    float4 g1 = *(const float4*)(g + t * 8 + 4);
    float4 b0 = *(const float4*)(bta + t * 8);
    float4 b1 = *(const float4*)(bta + t * 8 + 4);
    float ov[8];
    ov[0] = (v[0] - mu) * r * g0.x + b0.x;
    ov[1] = (v[1] - mu) * r * g0.y + b0.y;
    ov[2] = (v[2] - mu) * r * g0.z + b0.z;
    ov[3] = (v[3] - mu) * r * g0.w + b0.w;
    ov[4] = (v[4] - mu) * r * g1.x + b1.x;
    ov[5] = (v[5] - mu) * r * g1.y + b1.y;
    ov[6] = (v[6] - mu) * r * g1.z + b1.z;
    ov[7] = (v[7] - mu) * r * g1.w + b1.w;
    *(float4*)(x + base) = *(float4*)&ov[0];
    *(float4*)(x + base + 4) = *(float4*)&ov[4];
    bf16x8 ob;
#pragma unroll
    for (int i = 0; i < 8; ++i) ob[i] = f2bf(ov[i]);
    *(bf16x8*)(xb + base) = ob;
}

// ---------------------------------------------------------------------------
extern "C" void kernel_launch(void* const* d_in, const int* in_sizes, int n_in,
                              void* d_out, int out_size, void* d_ws, size_t ws_size,
                              hipStream_t stream) {
    const float* x_in  = (const float*)d_in[0];
    const int*   mask  = (const int*)d_in[3];
    const float* Wqkv  = (const float*)d_in[4];
    const float* Wfc   = (const float*)d_in[5];
    const float* bfc   = (const float*)d_in[6];
    const float* ln1_g = (const float*)d_in[7];
    const float* ln1_b = (const float*)d_in[8];
    const float* ln2_g = (const float*)d_in[9];
    const float* ln2_b = (const float*)d_in[10];
    const float* W1    = (const float*)d_in[11];
    const float* b1    = (const float*)d_in[12];
    const float* W2    = (const float*)d_in[13];
    const float* b2    = (const float*)d_in[14];

    float* x = (float*)d_out;  // fp32 activation master lives in d_out

    char* ws = (char*)d_ws;
    size_t ofs = 0;
    int*   pos   = (int*)ws;                 ofs += 65536;
    float* tmp   = (float*)(ws + ofs);       ofs += (size_t)ROWS * DMODEL * 4;
    short* xb    = (short*)(ws + ofs);       ofs += (size_t)ROWS * DMODEL * 2;
    short* qkvb  = (short*)(ws + ofs);
    short* hb    = (short*)(ws + ofs);       // aliases qkvb..obuf (disjoint lifetime)
    ofs += (size_t)ROWS * 3 * DMODEL * 2;
    short* obuf  = (short*)(ws + ofs);       ofs += (size_t)ROWS * DMODEL * 2;
    short* WqkvT = (short*)(ws + ofs);       ofs += (size_t)LAYERS * DMODEL * 3 * DMODEL * 2;
    short* WfcT  = (short*)(ws + ofs);       ofs += (size_t)LAYERS * DMODEL * DMODEL * 2;
    short* W1T   = (short*)(ws + ofs);       ofs += (size_t)LAYERS * DMODEL * FFDIM * 2;
    short* W2T   = (short*)(ws + ofs);       ofs += (size_t)LAYERS * FFDIM * DMODEL * 2;

    wtrans_kernel<<<dim3(3 * DMODEL / 32, DMODEL / 32, LAYERS), dim3(32, 8), 0, stream>>>(
        Wqkv, WqkvT, DMODEL, 3 * DMODEL);
    wtrans_kernel<<<dim3(DMODEL / 32, DMODEL / 32, LAYERS), dim3(32, 8), 0, stream>>>(
        Wfc, WfcT, DMODEL, DMODEL);
    wtrans_kernel<<<dim3(FFDIM / 32, DMODEL / 32, LAYERS), dim3(32, 8), 0, stream>>>(
        W1, W1T, DMODEL, FFDIM);
    wtrans_kernel<<<dim3(DMODEL / 32, FFDIM / 32, LAYERS), dim3(32, 8), 0, stream>>>(
        W2, W2T, FFDIM, DMODEL);

    pos_scan_kernel<<<BATCH, SEQ, 0, stream>>>(mask, pos);
    add_pos_kernel<<<ROWS, 128, 0, stream>>>(x_in, pos, x, xb);

    for (int l = 0; l < LAYERS; ++l) {
        const short* wqkvT_l = WqkvT + (size_t)l * DMODEL * 3 * DMODEL;
        const short* wfcT_l  = WfcT + (size_t)l * DMODEL * DMODEL;
        const short* w1T_l   = W1T + (size_t)l * DMODEL * FFDIM;
        const short* w2T_l   = W2T + (size_t)l * FFDIM * DMODEL;
        const float* bfc_l   = bfc + (size_t)l * DMODEL;
        const float* b1_l    = b1 + (size_t)l * FFDIM;
        const float* b2_l    = b2 + (size_t)l * DMODEL;

        // qkv = x @ Wqkv  (bf16 out), N=1536: 768 blocks
        gemm_bf16_kernel<true, false, false><<<dim3(3 * DMODEL / 128, ROWS / 128), 256, 0, stream>>>(
            xb, wqkvT_l, nullptr, qkvb, ROWS, 3 * DMODEL, DMODEL);
        attn_mfma_kernel<<<dim3(SEQ / QTILE, BATCH * NHEAD), 512, 0, stream>>>(qkvb, mask, obuf);
        // tmp = obuf @ Wfc + bfc  (fp32 out), N=512: m64 tile -> 512 blocks
        gemm_bf16_m64_kernel<false, true, false><<<dim3(DMODEL / 128, ROWS / 64), 256, 0, stream>>>(
            obuf, wfcT_l, bfc_l, tmp, ROWS, DMODEL, DMODEL);
        ln_kernel<<<ROWS, 64, 0, stream>>>(tmp, x, xb, ln1_g + (size_t)l * DMODEL,
                                           ln1_b + (size_t)l * DMODEL);
        // h = relu(x @ W1 + b1)  (bf16 out), N=2048: 1024 blocks
        gemm_bf16_kernel<true, true, true><<<dim3(FFDIM / 128, ROWS / 128), 256, 0, stream>>>(
            xb, w1T_l, b1_l, hb, ROWS, FFDIM, DMODEL);
        // tmp = h @ W2 + b2  (fp32 out), N=512: m64 tile -> 512 blocks
        gemm_bf16_m64_kernel<false, true, false><<<dim3(DMODEL / 128, ROWS / 64), 256, 0, stream>>>(
            hb, w2T_l, b2_l, tmp, ROWS, DMODEL, FFDIM);
        ln_kernel<<<ROWS, 64, 0, stream>>>(tmp, x, xb, ln2_g + (size_t)l * DMODEL,
                                           ln2_b + (size_t)l * DMODEL);
    }
}

// Round 6
// 992.646 us; speedup vs baseline: 1.0245x; 1.0245x over previous
//
#include <hip/hip_runtime.h>
#include <math.h>

// Problem constants
#define LAYERS 6
#define DMODEL 512
#define NHEAD 8
#define DHEAD 64
#define FFDIM 2048
#define BATCH 8
#define SEQ 1024
#define ROWS (BATCH * SEQ)   // 8192
#define EPS 1e-5f

typedef __attribute__((ext_vector_type(8))) short bf16x8;
typedef __attribute__((ext_vector_type(4))) float f32x4;
typedef __attribute__((ext_vector_type(16))) float f32x16;

__device__ inline short f2bf(float f) {
    union { float f; unsigned u; } v; v.f = f;
    unsigned r = (v.u + 0x7FFFu + ((v.u >> 16) & 1u)) >> 16;
    return (short)r;
}

// async global(bf16,16B) -> LDS staging; data lands at wave-uniform base + lane*16
#define GLOAD_LDS16(g, l)                                                      \
    __builtin_amdgcn_global_load_lds(                                          \
        (__attribute__((address_space(1))) void*)(g),                          \
        (__attribute__((address_space(3))) void*)(l), 16, 0, 0)

// XCD-chunked bijective block swizzle (nwg % 8 == 0 for all call sites):
// hw block h runs on XCD h%8; give XCD x the contiguous tile chunk
// [x*chunk, (x+1)*chunk) so A/B panels are reused within one XCD's L2.
#define XCD_SWIZZLE(TM, TN)                                                    \
    const int gx_ = gridDim.x;                                                 \
    const int bid_ = blockIdx.x + gx_ * blockIdx.y;                            \
    const int chunk_ = (gx_ * gridDim.y) >> 3;                                 \
    const int nb_ = (bid_ & 7) * chunk_ + (bid_ >> 3);                         \
    const int m0 = (nb_ / gx_) * (TM);                                         \
    const int n0 = (nb_ % gx_) * (TN);

// ---------------------------------------------------------------------------
// Weight transpose + fp32->bf16: src [L][K][N] f32 -> dst [L][N][K] bf16
// ---------------------------------------------------------------------------
__global__ void wtrans_kernel(const float* __restrict__ src, short* __restrict__ dst,
                              int K, int N) {
    __shared__ float t[32][33];
    const size_t mofs = (size_t)blockIdx.z * K * N;
    src += mofs; dst += mofs;
    int n0 = blockIdx.x * 32, k0 = blockIdx.y * 32;
    int tx = threadIdx.x, ty = threadIdx.y;
#pragma unroll
    for (int i = 0; i < 4; ++i)
        t[ty + 8 * i][tx] = src[(size_t)(k0 + ty + 8 * i) * N + n0 + tx];
    __syncthreads();
#pragma unroll
    for (int i = 0; i < 4; ++i)
        dst[(size_t)(n0 + ty + 8 * i) * K + k0 + tx] = f2bf(t[tx][ty + 8 * i]);
}

// ---------------------------------------------------------------------------
// Positional scan
// ---------------------------------------------------------------------------
__global__ void pos_scan_kernel(const int* __restrict__ mask, int* __restrict__ pos) {
    __shared__ int sm[SEQ];
    int b = blockIdx.x;
    int t = threadIdx.x;
    int v = (mask[b * SEQ + t] != 0) ? 1 : 0;
    sm[t] = v;
    __syncthreads();
    for (int off = 1; off < SEQ; off <<= 1) {
        int add = (t >= off) ? sm[t - off] : 0;
        __syncthreads();
        sm[t] += add;
        __syncthreads();
    }
    pos[b * SEQ + t] = sm[t] * v;
}

// ---------------------------------------------------------------------------
// x = x_in + sin_pos_table[pos]; writes fp32 master + bf16 copy
// ---------------------------------------------------------------------------
__global__ void add_pos_kernel(const float* __restrict__ xin, const int* __restrict__ pos,
                               float* __restrict__ xout, short* __restrict__ xb) {
    int bs = blockIdx.x;
    int t = threadIdx.x;
    int p = pos[bs];
    int d0 = t * 4;
    const float C = -logf(10000.0f) * (1.0f / 255.0f);  // half-1 = 255
    float4 xv = *(const float4*)(xin + (size_t)bs * DMODEL + d0);
    float e[4];
#pragma unroll
    for (int j = 0; j < 4; ++j) {
        int d = d0 + j;
        if (p == 0) {
            e[j] = 0.0f;
        } else {
            int dd = (d < 256) ? d : d - 256;
            float freq = expf((float)dd * C);
            float ang = (float)p * freq;
            e[j] = (d < 256) ? sinf(ang) : cosf(ang);
        }
    }
    float4 ov;
    ov.x = xv.x + e[0]; ov.y = xv.y + e[1]; ov.z = xv.z + e[2]; ov.w = xv.w + e[3];
    *(float4*)(xout + (size_t)bs * DMODEL + d0) = ov;
    short4 sb;
    sb.x = f2bf(ov.x); sb.y = f2bf(ov.y); sb.z = f2bf(ov.z); sb.w = f2bf(ov.w);
    *(short4*)(xb + (size_t)bs * DMODEL + d0) = sb;
}

// ===========================================================================
// LDS k-granule swizzle (all GEMM kernels):
//   store: staging lane (r=lane>>2, pos=lane&3) fetches global granule
//          g' = (pos - (r>>1)) & 3  -> granule q of row m lands at LDS
//          position (q + ((m&15)>>1)) & 3.
//   read:  fragment (m, quad) at granule position (quad + (lr>>1)) & 3
//          (valid since m&15 == lr for all fragment rows).
//   Result: conflict-free ds_read_b128.
// ===========================================================================

// ---------------------------------------------------------------------------
// bf16 MFMA GEMM, 128x128 tile, BK=32, 256 thr, single-barrier double-buffer.
// C[M,N] = A[M,K] @ BT[N,K]^T (+bias)(+relu).
// ---------------------------------------------------------------------------
template <bool OUTBF16, bool BIAS, bool RELU>
__global__ __launch_bounds__(256) void gemm_bf16_kernel(const short* __restrict__ A,
                                                        const short* __restrict__ BT,
                                                        const float* __restrict__ bias,
                                                        void* __restrict__ Cv,
                                                        int M, int N, int K) {
    __shared__ __attribute__((aligned(16))) short Asm[2][128 * 32];
    __shared__ __attribute__((aligned(16))) short Bsm[2][128 * 32];
    const int tid = threadIdx.x;
    const int w = tid >> 6;
    const int lane = tid & 63;
    const int quad = lane >> 4;
    const int lr = lane & 15;
    XCD_SWIZZLE(128, 128)
    const int wm = (w >> 1) * 64;
    const int wn = (w & 1) * 64;

    // staging: 8 segments of 16 rows; wave w owns segs {2w, 2w+1}
    const int segr = lane >> 2;
    const int segk = (((lane & 3) - (lane >> 3)) & 3) * 8;  // swizzled source granule
    const int sA0 = w * 2, sA1 = w * 2 + 1;
    const short* gA0 = A + (size_t)(m0 + sA0 * 16 + segr) * K + segk;
    const short* gA1 = A + (size_t)(m0 + sA1 * 16 + segr) * K + segk;
    const short* gB0 = BT + (size_t)(n0 + sA0 * 16 + segr) * K + segk;
    const short* gB1 = BT + (size_t)(n0 + sA1 * 16 + segr) * K + segk;
    const int lofs0 = sA0 * 512 + lane * 8;
    const int lofs1 = sA1 * 512 + lane * 8;
    const int gp = ((quad + (lr >> 1)) & 3) * 8;            // swizzled read position

    f32x4 acc[4][4];
#pragma unroll
    for (int i = 0; i < 4; ++i)
#pragma unroll
        for (int j = 0; j < 4; ++j) { acc[i][j][0] = 0.f; acc[i][j][1] = 0.f; acc[i][j][2] = 0.f; acc[i][j][3] = 0.f; }

    GLOAD_LDS16(gA0, &Asm[0][lofs0]);
    GLOAD_LDS16(gA1, &Asm[0][lofs1]);
    GLOAD_LDS16(gB0, &Bsm[0][lofs0]);
    GLOAD_LDS16(gB1, &Bsm[0][lofs1]);

    const int nk = K >> 5;
    for (int i = 0; i < nk; ++i) {
        __syncthreads();
        if (i + 1 < nk) {
            const int k1 = (i + 1) * 32;
            const int nb = (i + 1) & 1;
            GLOAD_LDS16(gA0 + k1, &Asm[nb][lofs0]);
            GLOAD_LDS16(gA1 + k1, &Asm[nb][lofs1]);
            GLOAD_LDS16(gB0 + k1, &Bsm[nb][lofs0]);
            GLOAD_LDS16(gB1 + k1, &Bsm[nb][lofs1]);
        }
        const int cur = i & 1;
        bf16x8 af[4], bfr[4];
#pragma unroll
        for (int mt = 0; mt < 4; ++mt)
            af[mt] = *(const bf16x8*)&Asm[cur][(wm + mt * 16 + lr) * 32 + gp];
#pragma unroll
        for (int nt = 0; nt < 4; ++nt)
            bfr[nt] = *(const bf16x8*)&Bsm[cur][(wn + nt * 16 + lr) * 32 + gp];
        __builtin_amdgcn_s_setprio(1);
#pragma unroll
        for (int mt = 0; mt < 4; ++mt)
#pragma unroll
            for (int nt = 0; nt < 4; ++nt)
                acc[mt][nt] = __builtin_amdgcn_mfma_f32_16x16x32_bf16(af[mt], bfr[nt], acc[mt][nt], 0, 0, 0);
        __builtin_amdgcn_s_setprio(0);
    }

    float bv[4];
    if (BIAS) {
#pragma unroll
        for (int nt = 0; nt < 4; ++nt) bv[nt] = bias[n0 + wn + nt * 16 + lr];
    }
#pragma unroll
    for (int mt = 0; mt < 4; ++mt)
#pragma unroll
        for (int nt = 0; nt < 4; ++nt)
#pragma unroll
            for (int r = 0; r < 4; ++r) {
                float v = acc[mt][nt][r];
                if (BIAS) v += bv[nt];
                if (RELU) v = fmaxf(v, 0.f);
                int row = m0 + wm + mt * 16 + quad * 4 + r;
                int col = n0 + wn + nt * 16 + lr;
                if (OUTBF16)
                    ((short*)Cv)[(size_t)row * N + col] = f2bf(v);
                else
                    ((float*)Cv)[(size_t)row * N + col] = v;
            }
}

// ---------------------------------------------------------------------------
// bf16 MFMA GEMM, 64x64 tile, BK=64, 256 thr = 4 waves (2x2 of 32x32).
// For the N=512 GEMMs: grid = 8 x 128 = 1024 blocks = 4 blocks/CU (the m64
// 64x128 tile was grid-limited to 2/CU -> latency-exposed barrier drains).
// Four independent barrier domains per CU hide each other's staging.
// LDS 32 KB (2 buf x 2 subtiles x (A 4KB + B 4KB)).
// ---------------------------------------------------------------------------
template <bool OUTBF16, bool BIAS, bool RELU>
__global__ __launch_bounds__(256) void gemm_bf16_s64_kernel(const short* __restrict__ A,
                                                            const short* __restrict__ BT,
                                                            const float* __restrict__ bias,
                                                            void* __restrict__ Cv,
                                                            int M, int N, int K) {
    __shared__ __attribute__((aligned(16))) short Asm[2][2][64 * 32];
    __shared__ __attribute__((aligned(16))) short Bsm[2][2][64 * 32];
    const int tid = threadIdx.x;
    const int w = tid >> 6;
    const int lane = tid & 63;
    const int quad = lane >> 4;
    const int lr = lane & 15;
    XCD_SWIZZLE(64, 64)
    const int wm = (w >> 1) * 32;
    const int wn = (w & 1) * 32;

    // staging: A = 4 segs (wave w -> seg w), B = 4 segs (wave w -> seg w)
    const int segr = lane >> 2;
    const int segk = (((lane & 3) - (lane >> 3)) & 3) * 8;  // swizzled source granule
    const short* gA = A + (size_t)(m0 + w * 16 + segr) * K + segk;
    const short* gB = BT + (size_t)(n0 + w * 16 + segr) * K + segk;
    const int lofs = w * 512 + lane * 8;
    const int gp = ((quad + (lr >> 1)) & 3) * 8;            // swizzled read position

    f32x4 acc[2][2];
#pragma unroll
    for (int i = 0; i < 2; ++i)
#pragma unroll
        for (int j = 0; j < 2; ++j) { acc[i][j][0] = 0.f; acc[i][j][1] = 0.f; acc[i][j][2] = 0.f; acc[i][j][3] = 0.f; }

#pragma unroll
    for (int kh = 0; kh < 2; ++kh) {
        GLOAD_LDS16(gA + kh * 32, &Asm[0][kh][lofs]);
        GLOAD_LDS16(gB + kh * 32, &Bsm[0][kh][lofs]);
    }

    const int nk = K >> 6;
    for (int i = 0; i < nk; ++i) {
        __syncthreads();
        if (i + 1 < nk) {
            const int k1 = (i + 1) * 64;
            const int nb = (i + 1) & 1;
#pragma unroll
            for (int kh = 0; kh < 2; ++kh) {
                GLOAD_LDS16(gA + k1 + kh * 32, &Asm[nb][kh][lofs]);
                GLOAD_LDS16(gB + k1 + kh * 32, &Bsm[nb][kh][lofs]);
            }
        }
        const int cur = i & 1;
#pragma unroll
        for (int kh = 0; kh < 2; ++kh) {
            bf16x8 af[2], bfr[2];
#pragma unroll
            for (int mt = 0; mt < 2; ++mt)
                af[mt] = *(const bf16x8*)&Asm[cur][kh][(wm + mt * 16 + lr) * 32 + gp];
#pragma unroll
            for (int nt = 0; nt < 2; ++nt)
                bfr[nt] = *(const bf16x8*)&Bsm[cur][kh][(wn + nt * 16 + lr) * 32 + gp];
            __builtin_amdgcn_s_setprio(1);
#pragma unroll
            for (int mt = 0; mt < 2; ++mt)
#pragma unroll
                for (int nt = 0; nt < 2; ++nt)
                    acc[mt][nt] = __builtin_amdgcn_mfma_f32_16x16x32_bf16(af[mt], bfr[nt], acc[mt][nt], 0, 0, 0);
            __builtin_amdgcn_s_setprio(0);
        }
    }

    float bv[2];
    if (BIAS) {
#pragma unroll
        for (int nt = 0; nt < 2; ++nt) bv[nt] = bias[n0 + wn + nt * 16 + lr];
    }
#pragma unroll
    for (int mt = 0; mt < 2; ++mt)
#pragma unroll
        for (int nt = 0; nt < 2; ++nt)
#pragma unroll
            for (int r = 0; r < 4; ++r) {
                float v = acc[mt][nt][r];
                if (BIAS) v += bv[nt];
                if (RELU) v = fmaxf(v, 0.f);
                int row = m0 + wm + mt * 16 + quad * 4 + r;
                int col = n0 + wn + nt * 16 + lr;
                if (OUTBF16)
                    ((short*)Cv)[(size_t)row * N + col] = f2bf(v);
                else
                    ((float*)Cv)[(size_t)row * N + col] = v;
            }
}

// ---------------------------------------------------------------------------
// bf16-MFMA flash attention v4b: 32x32x16 MFMA shape. QTILE=256, 512 thr =
// 8 waves x 32 q-rows. Swapped QK^T (S^T = mfma(K, Q)) leaves P^T[key][q]
// in registers; the PV A-fragment is built fully IN-REGISTER via
// cvt_pk_bf16 + cross-half shfl_xor(32) + select (no P LDS round-trip).
// Mask+shift folded into the exp ARGUMENT (additive -8 / -1e30 bias table).
// s_setprio(1) around MFMA clusters (T5). No-rescale softmax (fixed shift 8,
// exact after normalization), double-buffered K/V staging, ONE barrier/tile.
//
// Layouts (mfma_f32_32x32x16_bf16):
//   A:  row = lane&31, k = (lane>>5)*8 + j   (4 VGPR = 8 bf16)
//   B:  col = lane&31, k = (lane>>5)*8 + j
//   C:  col = lane&31, row = (reg&3) + 8*(reg>>2) + 4*(lane>>5)
// ---------------------------------------------------------------------------
#define QTILE 256
__global__ __launch_bounds__(512, 2) void attn_mfma_kernel(const short* __restrict__ qkv,
                                                           const int* __restrict__ mask,
                                                           short* __restrict__ o) {
    __shared__ __attribute__((aligned(16))) short Ks[2][64][72];    // [key][d]
    __shared__ __attribute__((aligned(16))) short Vt[2][64][72];    // [d][key]
    __shared__ __attribute__((aligned(16))) float Msf[2][64];

    const int qt = blockIdx.x;          // 0..3
    const int bh = blockIdx.y;          // 0..63
    const int b = bh >> 3, h = bh & 7;
    const int tid = threadIdx.x;
    const int w = tid >> 6;             // wave 0..7
    const int lane = tid & 63;
    const int c31 = lane & 31;
    const int hi = lane >> 5;
    const size_t seqrow = (size_t)b * SEQ;

    // Q as B-operand: lane holds Q^T[k=d=16ks+8hi+j][q=c31]
    bf16x8 qf[4];
#pragma unroll
    for (int ks = 0; ks < 4; ++ks)
        qf[ks] = *(const bf16x8*)(qkv +
            (seqrow + qt * QTILE + w * 32 + c31) * (3 * DMODEL)
            + h * DHEAD + ks * 16 + hi * 8);

    const bool isK = (tid < 256);
    const int st = isK ? tid : tid - 256;
    const int kkey = st >> 2;
    const int kg = (st & 3) * 8;
    const int vkp = st & 31;
    const int vdg = st >> 5;
    const short* gK = qkv + (seqrow + kkey) * (3 * DMODEL) + DMODEL + h * DHEAD + kg;
    const short* gV = qkv + (seqrow + 2 * vkp) * (3 * DMODEL) + 2 * DMODEL + h * DHEAD + vdg * 8;

    bf16x8 r0, r1;
    int mreg = 0;

    {
        if (isK) {
            r0 = *(const bf16x8*)(gK);
            r1 = *(const bf16x8*)(gK + 32);
        } else {
            r0 = *(const bf16x8*)(gV);
            r1 = *(const bf16x8*)(gV + 3 * DMODEL);
        }
        if (tid < 64) mreg = mask[seqrow + tid];
        if (isK) {
            *(bf16x8*)&Ks[0][kkey][kg] = r0;
            *(bf16x8*)&Ks[0][kkey][kg + 32] = r1;
        } else {
#pragma unroll
            for (int i = 0; i < 8; ++i) {
                short2 p; p.x = r0[i]; p.y = r1[i];
                *(short2*)&Vt[0][vdg * 8 + i][vkp * 2] = p;
            }
        }
        if (tid < 64) Msf[0][tid] = mreg ? -8.0f : -1e30f;   // additive exp bias
    }
    __syncthreads();

    f32x16 O0, O1;
    float rs = 0.f;
#pragma unroll
    for (int i = 0; i < 16; ++i) { O0[i] = 0.f; O1[i] = 0.f; }

    for (int kt = 0; kt < 16; ++kt) {
        const int cur = kt & 1;
        {
            const size_t ofs = (size_t)((kt + 1) & 15) * 64 * (3 * DMODEL);
            if (isK) {
                r0 = *(const bf16x8*)(gK + ofs);
                r1 = *(const bf16x8*)(gK + ofs + 32);
            } else {
                r0 = *(const bf16x8*)(gV + ofs);
                r1 = *(const bf16x8*)(gV + ofs + 3 * DMODEL);
            }
            if (tid < 64) mreg = mask[seqrow + ((kt + 1) & 15) * 64 + tid];
        }

        // QK^T: S^T[key][q], two 32-key tiles
        f32x16 S0, S1;
#pragma unroll
        for (int i = 0; i < 16; ++i) { S0[i] = 0.f; S1[i] = 0.f; }
        __builtin_amdgcn_s_setprio(1);
#pragma unroll
        for (int ks = 0; ks < 4; ++ks) {
            bf16x8 k0 = *(const bf16x8*)&Ks[cur][c31][ks * 16 + hi * 8];
            bf16x8 k1 = *(const bf16x8*)&Ks[cur][32 + c31][ks * 16 + hi * 8];
            S0 = __builtin_amdgcn_mfma_f32_32x32x16_bf16(k0, qf[ks], S0, 0, 0, 0);
            S1 = __builtin_amdgcn_mfma_f32_32x32x16_bf16(k1, qf[ks], S1, 0, 0, 0);
        }
        __builtin_amdgcn_s_setprio(0);

        // softmax (no rescale; additive bias = -8 or -1e30) + pack to bf16.
        // S reg r holds key = (r&3) + 8*(r>>2) + 4*hi (+32 for S1).
        unsigned pkd[2][8];
#pragma unroll
        for (int g = 0; g < 4; ++g) {
            f32x4 m0 = *(const f32x4*)&Msf[cur][g * 8 + hi * 4];
            f32x4 m1 = *(const f32x4*)&Msf[cur][32 + g * 8 + hi * 4];
            float p0[4], p1[4];
#pragma unroll
            for (int j = 0; j < 4; ++j) {
                p0[j] = __expf(S0[g * 4 + j] + m0[j]);
                p1[j] = __expf(S1[g * 4 + j] + m1[j]);
                rs += p0[j] + p1[j];
            }
            asm("v_cvt_pk_bf16_f32 %0, %1, %2" : "=v"(pkd[0][g * 2])     : "v"(p0[0]), "v"(p0[1]));
            asm("v_cvt_pk_bf16_f32 %0, %1, %2" : "=v"(pkd[0][g * 2 + 1]) : "v"(p0[2]), "v"(p0[3]));
            asm("v_cvt_pk_bf16_f32 %0, %1, %2" : "=v"(pkd[1][g * 2])     : "v"(p1[0]), "v"(p1[1]));
            asm("v_cvt_pk_bf16_f32 %0, %1, %2" : "=v"(pkd[1][g * 2 + 1]) : "v"(p1[2]), "v"(p1[3]));
        }

        // PV: build A-frag per ks in-register.
#pragma unroll
        for (int ks = 0; ks < 4; ++ks) {
            const int k2 = ks >> 1;
            const int i0 = (ks & 1) * 4;
            unsigned c0a = pkd[k2][i0 + 0], c0b = pkd[k2][i0 + 1];
            unsigned c1a = pkd[k2][i0 + 2], c1b = pkd[k2][i0 + 3];
            unsigned x1a = (unsigned)__shfl_xor((int)c1a, 32);
            unsigned x1b = (unsigned)__shfl_xor((int)c1b, 32);
            unsigned x0a = (unsigned)__shfl_xor((int)c0a, 32);
            unsigned x0b = (unsigned)__shfl_xor((int)c0b, 32);
            union { unsigned u[4]; bf16x8 v; } pb;
            pb.u[0] = hi ? x1a : c0a;   // d0: lo->own C0 ; hi->partner C1
            pb.u[1] = hi ? x1b : c0b;   // d1
            pb.u[2] = hi ? c1a : x0a;   // d2: lo->partner C0 ; hi->own C1
            pb.u[3] = hi ? c1b : x0b;   // d3
            bf16x8 v0 = *(const bf16x8*)&Vt[cur][c31][ks * 16 + hi * 8];
            bf16x8 v1 = *(const bf16x8*)&Vt[cur][32 + c31][ks * 16 + hi * 8];
            __builtin_amdgcn_s_setprio(1);
            O0 = __builtin_amdgcn_mfma_f32_32x32x16_bf16(pb.v, v0, O0, 0, 0, 0);
            O1 = __builtin_amdgcn_mfma_f32_32x32x16_bf16(pb.v, v1, O1, 0, 0, 0);
            __builtin_amdgcn_s_setprio(0);
        }

        {
            const int nb = cur ^ 1;
            if (isK) {
                *(bf16x8*)&Ks[nb][kkey][kg] = r0;
                *(bf16x8*)&Ks[nb][kkey][kg + 32] = r1;
            } else {
#pragma unroll
                for (int i = 0; i < 8; ++i) {
                    short2 p; p.x = r0[i]; p.y = r1[i];
                    *(short2*)&Vt[nb][vdg * 8 + i][vkp * 2] = p;
                }
            }
            if (tid < 64) Msf[nb][tid] = mreg ? -8.0f : -1e30f;
        }
        __syncthreads();
    }

    // rs: lane holds partial denominator for q=c31 over its own-half keys.
    rs += __shfl_xor(rs, 32);   // full denominator for q=c31, all lanes

#pragma unroll
    for (int r = 0; r < 16; ++r) {
        const int qr = (r & 3) + 8 * (r >> 2) + 4 * hi;   // O row = q
        const float inv = 1.0f / __shfl(rs, qr);
        const int row = qt * QTILE + w * 32 + qr;
        o[(seqrow + row) * DMODEL + h * DHEAD + c31]      = f2bf(O0[r] * inv);
        o[(seqrow + row) * DMODEL + h * DHEAD + 32 + c31] = f2bf(O1[r] * inv);
    }
}

// ---------------------------------------------------------------------------
// x = LayerNorm(tmp + x) * g + b; writes fp32 master (in-place) + bf16 copy
// ---------------------------------------------------------------------------
__global__ __launch_bounds__(64) void ln_kernel(const float* __restrict__ tmp,
                                                float* __restrict__ x,
                                                short* __restrict__ xb,
                                                const float* __restrict__ g,
                                                const float* __restrict__ bta) {
    const int row = blockIdx.x;
    const int t = threadIdx.x;
    const size_t base = (size_t)row * DMODEL + t * 8;
    float4 x0 = *(const float4*)(x + base);
    float4 x1 = *(const float4*)(x + base + 4);
    float4 t0 = *(const float4*)(tmp + base);
    float4 t1 = *(const float4*)(tmp + base + 4);
    float v[8];
    v[0] = x0.x + t0.x; v[1] = x0.y + t0.y; v[2] = x0.z + t0.z; v[3] = x0.w + t0.w;
    v[4] = x1.x + t1.x; v[5] = x1.y + t1.y; v[6] = x1.z + t1.z; v[7] = x1.w + t1.w;
    float s = 0.f, sq = 0.f;
#pragma unroll
    for (int i = 0; i < 8; ++i) { s += v[i]; sq += v[i] * v[i]; }
#pragma unroll
    for (int off = 1; off < 64; off <<= 1) {
        s += __shfl_xor(s, off);
        sq += __shfl_xor(sq, off);
    }
    float mu = s * (1.0f / DMODEL);
    float var = sq * (1.0f / DMODEL) - mu * mu;
    float r = rsqrtf(var + EPS);
    float4 g0 = *(const float4*)(g + t * 8);
    float4 g1 = *(const float4*)(g + t * 8 + 4);
    float4 b0 = *(const float4*)(bta + t * 8);
    float4 b1 = *(const float4*)(bta + t * 8 + 4);
    float ov[8];
    ov[0] = (v[0] - mu) * r * g0.x + b0.x;
    ov[1] = (v[1] - mu) * r * g0.y + b0.y;
    ov[2] = (v[2] - mu) * r * g0.z + b0.z;
    ov[3] = (v[3] - mu) * r * g0.w + b0.w;
    ov[4] = (v[4] - mu) * r * g1.x + b1.x;
    ov[5] = (v[5] - mu) * r * g1.y + b1.y;
    ov[6] = (v[6] - mu) * r * g1.z + b1.z;
    ov[7] = (v[7] - mu) * r * g1.w + b1.w;
    *(float4*)(x + base) = *(float4*)&ov[0];
    *(float4*)(x + base + 4) = *(float4*)&ov[4];
    bf16x8 ob;
#pragma unroll
    for (int i = 0; i < 8; ++i) ob[i] = f2bf(ov[i]);
    *(bf16x8*)(xb + base) = ob;
}

// ---------------------------------------------------------------------------
extern "C" void kernel_launch(void* const* d_in, const int* in_sizes, int n_in,
                              void* d_out, int out_size, void* d_ws, size_t ws_size,
                              hipStream_t stream) {
    const float* x_in  = (const float*)d_in[0];
    const int*   mask  = (const int*)d_in[3];
    const float* Wqkv  = (const float*)d_in[4];
    const float* Wfc   = (const float*)d_in[5];
    const float* bfc   = (const float*)d_in[6];
    const float* ln1_g = (const float*)d_in[7];
    const float* ln1_b = (const float*)d_in[8];
    const float* ln2_g = (const float*)d_in[9];
    const float* ln2_b = (const float*)d_in[10];
    const float* W1    = (const float*)d_in[11];
    const float* b1    = (const float*)d_in[12];
    const float* W2    = (const float*)d_in[13];
    const float* b2    = (const float*)d_in[14];

    float* x = (float*)d_out;  // fp32 activation master lives in d_out

    char* ws = (char*)d_ws;
    size_t ofs = 0;
    int*   pos   = (int*)ws;                 ofs += 65536;
    float* tmp   = (float*)(ws + ofs);       ofs += (size_t)ROWS * DMODEL * 4;
    short* xb    = (short*)(ws + ofs);       ofs += (size_t)ROWS * DMODEL * 2;
    short* qkvb  = (short*)(ws + ofs);
    short* hb    = (short*)(ws + ofs);       // aliases qkvb..obuf (disjoint lifetime)
    ofs += (size_t)ROWS * 3 * DMODEL * 2;
    short* obuf  = (short*)(ws + ofs);       ofs += (size_t)ROWS * DMODEL * 2;
    short* WqkvT = (short*)(ws + ofs);       ofs += (size_t)LAYERS * DMODEL * 3 * DMODEL * 2;
    short* WfcT  = (short*)(ws + ofs);       ofs += (size_t)LAYERS * DMODEL * DMODEL * 2;
    short* W1T   = (short*)(ws + ofs);       ofs += (size_t)LAYERS * DMODEL * FFDIM * 2;
    short* W2T   = (short*)(ws + ofs);       ofs += (size_t)LAYERS * FFDIM * DMODEL * 2;

    wtrans_kernel<<<dim3(3 * DMODEL / 32, DMODEL / 32, LAYERS), dim3(32, 8), 0, stream>>>(
        Wqkv, WqkvT, DMODEL, 3 * DMODEL);
    wtrans_kernel<<<dim3(DMODEL / 32, DMODEL / 32, LAYERS), dim3(32, 8), 0, stream>>>(
        Wfc, WfcT, DMODEL, DMODEL);
    wtrans_kernel<<<dim3(FFDIM / 32, DMODEL / 32, LAYERS), dim3(32, 8), 0, stream>>>(
        W1, W1T, DMODEL, FFDIM);
    wtrans_kernel<<<dim3(DMODEL / 32, FFDIM / 32, LAYERS), dim3(32, 8), 0, stream>>>(
        W2, W2T, FFDIM, DMODEL);

    pos_scan_kernel<<<BATCH, SEQ, 0, stream>>>(mask, pos);
    add_pos_kernel<<<ROWS, 128, 0, stream>>>(x_in, pos, x, xb);

    for (int l = 0; l < LAYERS; ++l) {
        const short* wqkvT_l = WqkvT + (size_t)l * DMODEL * 3 * DMODEL;
        const short* wfcT_l  = WfcT + (size_t)l * DMODEL * DMODEL;
        const short* w1T_l   = W1T + (size_t)l * DMODEL * FFDIM;
        const short* w2T_l   = W2T + (size_t)l * FFDIM * DMODEL;
        const float* bfc_l   = bfc + (size_t)l * DMODEL;
        const float* b1_l    = b1 + (size_t)l * FFDIM;
        const float* b2_l    = b2 + (size_t)l * DMODEL;

        // qkv = x @ Wqkv  (bf16 out), N=1536: 768 blocks = 3/CU
        gemm_bf16_kernel<true, false, false><<<dim3(3 * DMODEL / 128, ROWS / 128), 256, 0, stream>>>(
            xb, wqkvT_l, nullptr, qkvb, ROWS, 3 * DMODEL, DMODEL);
        attn_mfma_kernel<<<dim3(SEQ / QTILE, BATCH * NHEAD), 512, 0, stream>>>(qkvb, mask, obuf);
        // tmp = obuf @ Wfc + bfc  (fp32 out), N=512: s64 tile -> 1024 blocks = 4/CU
        gemm_bf16_s64_kernel<false, true, false><<<dim3(DMODEL / 64, ROWS / 64), 256, 0, stream>>>(
            obuf, wfcT_l, bfc_l, tmp, ROWS, DMODEL, DMODEL);
        ln_kernel<<<ROWS, 64, 0, stream>>>(tmp, x, xb, ln1_g + (size_t)l * DMODEL,
                                           ln1_b + (size_t)l * DMODEL);
        // h = relu(x @ W1 + b1)  (bf16 out), N=2048: 1024 blocks = 4/CU
        gemm_bf16_kernel<true, true, true><<<dim3(FFDIM / 128, ROWS / 128), 256, 0, stream>>>(
            xb, w1T_l, b1_l, hb, ROWS, FFDIM, DMODEL);
        // tmp = h @ W2 + b2  (fp32 out), N=512: s64 tile -> 1024 blocks = 4/CU
        gemm_bf16_s64_kernel<false, true, false><<<dim3(DMODEL / 64, ROWS / 64), 256, 0, stream>>>(
            hb, w2T_l, b2_l, tmp, ROWS, DMODEL, FFDIM);
        ln_kernel<<<ROWS, 64, 0, stream>>>(tmp, x, xb, ln2_g + (size_t)l * DMODEL,
                                           ln2_b + (size_t)l * DMODEL);
    }
}